// Round 10
// baseline (251.870 us; speedup 1.0000x reference)
//
#include <hip/hip_runtime.h>
#include <math.h>

#define N_NODES 50000
#define N_EDGES 800000
#define NE_TOT  (N_EDGES + N_NODES)   // edges + self-loops
#define IN_DIM  128
#define H1 2
#define C1 16
#define D1 (H1*C1)   // 32
#define D2 64        // H2=1, C2=64
#define SLOPE 0.2f
#define CAP 64       // ELL row capacity; max degree ~ Poisson(16)+1 ~ 41 << 64

#define GROUPS 8
#define GRANGE (N_NODES / GROUPS)      // 6250 dst nodes per group
#define SB_PER_G 208                   // scatter blocks per group
#define SCAT_TOT (GROUPS * SB_PER_G)   // 1664
#define SCAT_STRIDE (SB_PER_G * 256)   // 53248 candidate positions per step
#define SWEEP 16                       // ceil(NE_TOT / SCAT_STRIDE)
#define G1_BLK   (N_NODES / 8)         // 6250 (gemm1: 8 rows/block)

__device__ __forceinline__ float lrelu(float v) { return v > 0.f ? v : SLOPE * v; }

// ---- mega: XCD-partitioned ELL scatter (ILP-batched) ∥ gemm1+scores1 ----
// Scatter: group g = blockIdx&7 owns dst range [g*GRANGE,(g+1)*GRANGE).
// Each thread first issues ALL 16 candidate dst loads branch-free (they
// pipeline in the VMEM queue), then handles the ~2 matching edges.
__global__ void mega_scatter_gemm1(const int* __restrict__ ei,
                                   int* __restrict__ cursor,   // zeroed; ends as deg
                                   int* __restrict__ slots,    // [N_NODES][CAP]
                                   const float* __restrict__ x,
                                   const float* __restrict__ W,
                                   const float* __restrict__ a_src,
                                   const float* __restrict__ a_dst,
                                   float* __restrict__ h,      // [N,32]
                                   float* __restrict__ s,      // [N,2]
                                   float* __restrict__ d) {    // [N,2]
    if (blockIdx.x < SCAT_TOT) {
        int g   = blockIdx.x & 7;
        int ord = blockIdx.x >> 3;              // 0..SB_PER_G-1
        int lo  = g * GRANGE;
        int e0  = ord * 256 + threadIdx.x;
        int dstv[SWEEP];
#pragma unroll
        for (int i = 0; i < SWEEP; ++i) {       // branch-free: 16 loads in flight
            int e = e0 + i * SCAT_STRIDE;
            dstv[i] = (e < N_EDGES) ? ei[N_EDGES + e]
                    : (e < NE_TOT ? e - N_EDGES : -1);
        }
#pragma unroll
        for (int i = 0; i < SWEEP; ++i) {
            int dst = dstv[i];
            if ((unsigned)(dst - lo) < (unsigned)GRANGE) {
                int e = e0 + i * SCAT_STRIDE;
                int src = (e < N_EDGES) ? ei[e] : dst;
                int pos = atomicAdd(&cursor[dst], 1);
                if (pos < CAP) slots[(dst << 6) + pos] = src;
            }
        }
        return;
    }
    // gemm1: h1 = x @ W1  [50000,128]x[128,32], 8 rows/block (50000 = 6250*8)
    int blk = blockIdx.x - SCAT_TOT;
    __shared__ float sW[IN_DIM * D1];           // 16 KB
    int t = threadIdx.x;                        // 256 threads
    for (int i = t; i < IN_DIM * D1; i += 256) sW[i] = W[i];
    __syncthreads();
    int col = t & 31;
    int row = blk * 8 + (t >> 5);
    const float* xr = x + (long long)row * IN_DIM;
    float acc = 0.f;
#pragma unroll 8
    for (int k = 0; k < IN_DIM; ++k) acc += xr[k] * sW[k * D1 + col];
    h[row * 32 + col] = acc;
    // scores1 epilogue: per-head dot with att vectors (16-lane butterfly)
    float p = acc * a_src[col];
    float q = acc * a_dst[col];
#pragma unroll
    for (int o = 8; o; o >>= 1) { p += __shfl_xor(p, o); q += __shfl_xor(q, o); }
    if ((col & 15) == 0) {
        int hd = col >> 4;
        s[row * 2 + hd] = p;
        d[row * 2 + hd] = q;
    }
}

// === fused layer 1 + gemm2 + scores2 ===
// Phases A-C: R6's bit-stable LDS-staging softmax/aggregate (ELL addressing).
// Epilogue: ELU -> LDS (same-wave RAW, no barrier), then lane = h2 column
// with gemm2's identical ascending-k loop; 64-lane butterfly for s2/d2.
__global__ void fused_l1_gemm2(const int* __restrict__ cur,
                               const int* __restrict__ slots,
                               const float* __restrict__ s,   // [N,2]
                               const float* __restrict__ d,   // [N,2]
                               const float* __restrict__ h,   // [N,32]
                               const float* __restrict__ bias,
                               const float* __restrict__ W2,  // [32,64]
                               const float* __restrict__ a2s, // [64]
                               const float* __restrict__ a2d, // [64]
                               float* __restrict__ h2,        // [N,64]
                               float* __restrict__ s2,        // [N]
                               float* __restrict__ d2) {      // [N]
    __shared__ float sW2[D1 * D2];                  // 8 KB
    __shared__ int   sh_sn[4][64];
    __shared__ float sh_p0[4][64];
    __shared__ float sh_p1[4][64];
    int t = threadIdx.x;
    for (int i = t; i < D1 * D2; i += 256) sW2[i] = W2[i];
    __syncthreads();
    int wave = t >> 6;
    int node = blockIdx.x * 4 + wave;               // grid exact: 12500*4
    int lane = t & 63;
    int deg = cur[node]; if (deg > CAP) deg = CAP;
    int start = node << 6, end = start + deg;
    float2 dn = ((const float2*)d)[node];
    // phase A: per-head segment max
    float m0 = -INFINITY, m1 = -INFINITY;
    for (int k = start + lane; k < end; k += 64) {
        float2 sv = ((const float2*)s)[slots[k]];
        m0 = fmaxf(m0, lrelu(sv.x + dn.x));
        m1 = fmaxf(m1, lrelu(sv.y + dn.y));
    }
    for (int o = 32; o; o >>= 1) {
        m0 = fmaxf(m0, __shfl_xor(m0, o));
        m1 = fmaxf(m1, __shfl_xor(m1, o));
    }
    // phase B: z-sum + LDS staging of per-edge pe
    float z0 = 0.f, z1 = 0.f;
    int k0 = start + lane;
    if (k0 < end) {
        int sn = slots[k0];
        float2 sv = ((const float2*)s)[sn];
        float p0 = expf(lrelu(sv.x + dn.x) - m0);
        float p1 = expf(lrelu(sv.y + dn.y) - m1);
        sh_sn[wave][lane] = sn;
        sh_p0[wave][lane] = p0;
        sh_p1[wave][lane] = p1;
        z0 = p0; z1 = p1;
    }
    for (int o = 32; o; o >>= 1) {
        z0 += __shfl_xor(z0, o);
        z1 += __shfl_xor(z1, o);
    }
    // phase C: channel-parallel accumulate, halves on even/odd edges
    int ch = lane & 31;
    int half = lane >> 5;
    int hd = ch >> 4;
    float acc = 0.f;
    for (int j = half; j < deg; j += 2) {
        float p = hd ? sh_p1[wave][j] : sh_p0[wave][j];
        acc += p * h[sh_sn[wave][j] * 32 + ch];
    }
    acc += __shfl_xor(acc, 32);
    // epilogue: normalize + bias + ELU -> LDS (reuse sh_p0 slice)
    if (lane < 32) {
        float zz = hd ? z1 : z0;
        float v = acc / (zz + 1e-16f) + bias[ch];
        sh_p0[wave][ch] = v > 0.f ? v : expf(v) - 1.f;   // ELU
    }
    // gemm2 (same-wave LDS RAW -> compiler-inserted lgkmcnt, no barrier)
    float hc = 0.f;
#pragma unroll
    for (int k = 0; k < D1; ++k) hc += sh_p0[wave][k] * sW2[k * D2 + lane];
    h2[node * 64 + lane] = hc;
    // scores2: 64-lane butterfly
    float p = hc * a2s[lane];
    float q = hc * a2d[lane];
#pragma unroll
    for (int o = 32; o; o >>= 1) { p += __shfl_xor(p, o); q += __shfl_xor(q, o); }
    if (lane == 0) { s2[node] = p; d2[node] = q; }
}

// ============ fused layer 2: softmax + aggregate + norm + bias ===============
__global__ void fused_layer2(const int* __restrict__ cur,
                             const int* __restrict__ slots,
                             const float* __restrict__ s,   // [N]
                             const float* __restrict__ d,   // [N]
                             const float* __restrict__ h,   // [N,64]
                             const float* __restrict__ bias,
                             float* __restrict__ out) {     // [N,64] final
    __shared__ int   sh_sn[4][64];
    __shared__ float sh_pe[4][64];
    int wave = threadIdx.x >> 6;
    int node = blockIdx.x * 4 + wave;
    if (node >= N_NODES) return;
    int lane = threadIdx.x & 63;
    int deg = cur[node]; if (deg > CAP) deg = CAP;
    int start = node << 6, end = start + deg;
    float dn = d[node];
    // phase A: segment max
    float m = -INFINITY;
    for (int k = start + lane; k < end; k += 64)
        m = fmaxf(m, lrelu(s[slots[k]] + dn));
    for (int o = 32; o; o >>= 1) m = fmaxf(m, __shfl_xor(m, o));
    // phase B: z-sum + LDS staging of per-edge pe
    float z = 0.f;
    int k0 = start + lane;
    if (k0 < end) {
        int sn = slots[k0];
        float pe = expf(lrelu(s[sn] + dn) - m);
        sh_sn[wave][lane] = sn;
        sh_pe[wave][lane] = pe;
        z = pe;
    }
    for (int o = 32; o; o >>= 1) z += __shfl_xor(z, o);
    // phase C: lane = channel; staged scalars, sequential edge order
    float acc = 0.f;
    for (int j = 0; j < deg; ++j) {
        acc += sh_pe[wave][j] * h[sh_sn[wave][j] * 64 + lane];
    }
    out[node * 64 + lane] = acc / (z + 1e-16f) + bias[lane];
}

extern "C" void kernel_launch(void* const* d_in, const int* in_sizes, int n_in,
                              void* d_out, int out_size, void* d_ws, size_t ws_size,
                              hipStream_t stream) {
    const float* x        = (const float*)d_in[0];
    const int*   ei       = (const int*)  d_in[1];   // [2, N_EDGES] int32
    const float* W1       = (const float*)d_in[2];
    const float* att_src1 = (const float*)d_in[3];
    const float* att_dst1 = (const float*)d_in[4];
    const float* bias1    = (const float*)d_in[5];
    const float* W2       = (const float*)d_in[6];
    const float* att_src2 = (const float*)d_in[7];
    const float* att_dst2 = (const float*)d_in[8];
    const float* bias2    = (const float*)d_in[9];
    float* out = (float*)d_out;

    // workspace layout
    float* w    = (float*)d_ws;
    float* h1   = w; w += (long long)N_NODES * D1;   // 1.6M f
    float* s1   = w; w += N_NODES * H1;
    float* d1v  = w; w += N_NODES * H1;
    float* h2   = w; w += (long long)N_NODES * D2;   // 3.2M f
    float* s2   = w; w += N_NODES;
    float* d2v  = w; w += N_NODES;
    int* iw     = (int*)w;
    int* cursor = iw; iw += N_NODES;                 // degree counters
    int* slots  = iw; iw += (long long)N_NODES * CAP; // ELL: 3.2M i (12.8 MB)

    const int B = 256;
    hipMemsetAsync(cursor, 0, N_NODES * sizeof(int), stream);
    mega_scatter_gemm1<<<SCAT_TOT + G1_BLK, B, 0, stream>>>(
        ei, cursor, slots, x, W1, att_src1, att_dst1, h1, s1, d1v);
    fused_l1_gemm2<<<N_NODES / 4, B, 0, stream>>>(
        cursor, slots, s1, d1v, h1, bias1, W2, att_src2, att_dst2, h2, s2, d2v);
    fused_layer2<<<(N_NODES + 3)/4, B, 0, stream>>>(cursor, slots, s2, d2v, h2, bias2, out);
}